// Round 3
// baseline (714.544 us; speedup 1.0000x reference)
//
#include <hip/hip_runtime.h>
#include <math.h>

// Chamfer distance, B=4, N=M=8192, fp32.
// Output layout (flat float32): dist1[B*N], dist2[B*M], idx1[B*N] (as float),
// idx2[B*M] (as float).
//
// R2: S=32 splits (2048 blocks -> 8 blocks/CU, full wave residency at
// VGPR<=64); faster merge (independent unrolled loads). Inner loop unchanged:
// exact per-op IEEE rounding (contract off) + strict-< first-occurrence
// argmin => absmax 0 vs numpy.

#define QPT 4         // queries per thread
#define BLK 256       // threads per block
#define QPB (QPT*BLK) // queries per block = 1024

__global__ __launch_bounds__(256, 8) void chamfer_main(
    const float* __restrict__ xyz1, const float* __restrict__ xyz2,
    float* __restrict__ pd, int* __restrict__ pi,
    int N, int M, int B, int S, int C)
{
#pragma clang fp contract(off)  // match numpy per-op IEEE rounding (no fma fuse)
    const int dir = blockIdx.z;          // 0: xyz1->xyz2, 1: xyz2->xyz1
    const float* q = dir ? xyz2 : xyz1;  // query cloud
    const float* r = dir ? xyz1 : xyz2;  // reference cloud
    const int Nq = dir ? M : N;
    const int Nr = dir ? N : M;
    const int b     = blockIdx.y / S;
    const int split = blockIdx.y % S;
    const int base  = split * C;         // this block's ref-index range [base, base+C)

    extern __shared__ float s[];         // C*3 floats

    // cooperative vectorized tile load (C%4==0 -> 16B aligned: C*3*4 % 16 == 0)
    {
        const float4* gv = (const float4*)(r + ((size_t)b * Nr + base) * 3);
        float4* sv = (float4*)s;
        const int elems4 = C * 3 / 4;
        for (int t = threadIdx.x; t < elems4; t += BLK) sv[t] = gv[t];
    }
    __syncthreads();

    // load 4 query points (stride-BLK within the block's query window)
    float qx[QPT], qy[QPT], qz[QPT];
    int qi[QPT];
    bool qv[QPT];
#pragma unroll
    for (int k = 0; k < QPT; ++k) {
        qi[k] = blockIdx.x * QPB + k * BLK + threadIdx.x;
        qv[k] = qi[k] < Nq;
        const float* qp = q + ((size_t)b * Nq + (qv[k] ? qi[k] : 0)) * 3;
        qx[k] = qp[0]; qy[k] = qp[1]; qz[k] = qp[2];
    }

    // 4 ref-phase accumulators per query: 16 independent min/argmin chains
    float bd[QPT][4];
    int   bi[QPT][4];
#pragma unroll
    for (int k = 0; k < QPT; ++k)
#pragma unroll
        for (int p = 0; p < 4; ++p) { bd[k][p] = INFINITY; bi[k][p] = base + p; }

    const float4* sv = (const float4*)s;
    const int iters = C / 4;
    for (int j4 = 0; j4 < iters; ++j4) {
        // 12 floats = 4 ref points; all lanes same address -> LDS broadcast
        float4 f0 = sv[3 * j4 + 0];
        float4 f1 = sv[3 * j4 + 1];
        float4 f2 = sv[3 * j4 + 2];
        float px[4] = { f0.x, f0.w, f1.z, f2.y };
        float py[4] = { f0.y, f1.x, f1.w, f2.z };
        float pz[4] = { f0.z, f1.y, f2.x, f2.w };
        const int jb = base + 4 * j4;
#pragma unroll
        for (int p = 0; p < 4; ++p) {
#pragma unroll
            for (int k = 0; k < QPT; ++k) {
                float dx = qx[k] - px[p];
                float dy = qy[k] - py[p];
                float dz = qz[k] - pz[p];
                float d = dx * dx + dy * dy + dz * dz;  // ((x+y)+z), per-op rn
                if (d < bd[k][p]) { bd[k][p] = d; bi[k][p] = jb + p; }
            }
        }
    }

    // merge 4 phases per query; tie-break on lower index (first occurrence)
    const size_t pbase = ((size_t)(dir * B + b) * S + split) * Nq;
#pragma unroll
    for (int k = 0; k < QPT; ++k) {
        float d0 = bd[k][0]; int i0 = bi[k][0];
        float d1 = bd[k][1]; int i1 = bi[k][1];
        float d2 = bd[k][2]; int i2 = bi[k][2];
        float d3 = bd[k][3]; int i3 = bi[k][3];
        if (d1 < d0 || (d1 == d0 && i1 < i0)) { d0 = d1; i0 = i1; }
        if (d3 < d2 || (d3 == d2 && i3 < i2)) { d2 = d3; i2 = i3; }
        if (d2 < d0 || (d2 == d0 && i2 < i0)) { d0 = d2; i0 = i2; }
        if (qv[k]) {
            pd[pbase + qi[k]] = d0;
            pi[pbase + qi[k]] = i0;
        }
    }
}

__global__ __launch_bounds__(256) void chamfer_merge(
    const float* __restrict__ pd, const int* __restrict__ pi,
    float* __restrict__ out, int N, int M, int B, int S)
{
    const int gid = blockIdx.x * blockDim.x + threadIdx.x;
    const int perDir0 = B * N, perDir1 = B * M;
    int dir, rem;
    if (gid < perDir0) { dir = 0; rem = gid; }
    else if (gid < perDir0 + perDir1) { dir = 1; rem = gid - perDir0; }
    else return;
    const int Nq = dir ? M : N;
    const int b = rem / Nq, i = rem % Nq;

    const size_t base = ((size_t)(dir * B + b) * S) * Nq + i;
    float bdv = INFINITY;
    int   biv = 0;
    // ascending split order + strict <  => first-occurrence argmin preserved.
    // unroll so all loads issue independently (latency overlap).
#pragma unroll 8
    for (int sp = 0; sp < S; ++sp) {
        float d = pd[base + (size_t)sp * Nq];
        int   ix = pi[base + (size_t)sp * Nq];
        if (d < bdv) { bdv = d; biv = ix; }
    }

    float* dist_out = out + (dir ? (size_t)B * N : 0);
    float* idx_out  = out + (size_t)B * N + (size_t)B * M + (dir ? (size_t)B * N : 0);
    dist_out[(size_t)b * Nq + i] = bdv;
    idx_out[(size_t)b * Nq + i]  = (float)biv;
}

extern "C" void kernel_launch(void* const* d_in, const int* in_sizes, int n_in,
                              void* d_out, int out_size, void* d_ws, size_t ws_size,
                              hipStream_t stream) {
    const float* xyz1 = (const float*)d_in[0];
    const float* xyz2 = (const float*)d_in[1];
    float* out = (float*)d_out;
    const int B = 4;
    const int N = in_sizes[0] / (B * 3);
    const int M = in_sizes[1] / (B * 3);
    const int NQ = (N > M ? N : M);
    const int NR = (N > M ? N : M);

    // pick split count S (pow2) such that partials fit in ws: 2*B*S*NQ*8 bytes
    int S = 32;
    while (S > 1 && (size_t)2 * B * S * NQ * 8 > ws_size) S >>= 1;
    while (NR % S) S >>= 1;  // require exact divisibility
    const int C = NR / S;

    float* pd = (float*)d_ws;
    int*   pi = (int*)((char*)d_ws + (size_t)2 * B * S * NQ * 4);

    dim3 grid((NQ + QPB - 1) / QPB, B * S, 2);
    size_t lds = (size_t)C * 3 * sizeof(float);
    chamfer_main<<<grid, dim3(BLK, 1, 1), lds, stream>>>(
        xyz1, xyz2, pd, pi, N, M, B, S, C);

    int totalOut = 2 * B * NQ;
    chamfer_merge<<<dim3((totalOut + 255) / 256, 1, 1), dim3(256, 1, 1), 0, stream>>>(
        pd, pi, out, N, M, B, S);
}

// Round 4
// 175.261 us; speedup vs baseline: 4.0770x; 4.0770x over previous
//
#include <hip/hip_runtime.h>
#include <math.h>

// Chamfer distance, B=4, N=M=8192, fp32.
// Output layout (flat float32): dist1[B*N], dist2[B*M], idx1[B*N] (as float),
// idx2[B*M] (as float).
//
// R3: revert R2's launch_bounds(256,8) — it forced 32 VGPRs and spilled the
// accumulators (1.4 GB scratch traffic, VALUBusy 18%). With (256,4) the
// compiler uses ~48 VGPRs; at <=64 VGPRs hardware co-schedules 8 blocks/CU
// anyway. Keep S=32 splits. Partials packed as u64 (dist_bits<<32 | idx):
// d>=0 makes float bits order-monotonic and u64-min tie-breaks to lower
// index == first-occurrence argmin. Halves merge traffic.

#define QPT 4         // queries per thread
#define BLK 256       // threads per block
#define QPB (QPT*BLK) // queries per block = 1024

__global__ __launch_bounds__(256, 4) void chamfer_main(
    const float* __restrict__ xyz1, const float* __restrict__ xyz2,
    unsigned long long* __restrict__ pp,
    int N, int M, int B, int S, int C)
{
#pragma clang fp contract(off)  // match numpy per-op IEEE rounding (no fma fuse)
    const int dir = blockIdx.z;          // 0: xyz1->xyz2, 1: xyz2->xyz1
    const float* q = dir ? xyz2 : xyz1;  // query cloud
    const float* r = dir ? xyz1 : xyz2;  // reference cloud
    const int Nq = dir ? M : N;
    const int Nr = dir ? N : M;
    const int b     = blockIdx.y / S;
    const int split = blockIdx.y % S;
    const int base  = split * C;         // this block's ref-index range [base, base+C)

    extern __shared__ float s[];         // C*3 floats

    // cooperative vectorized tile load (C%4==0 -> byte count divisible by 16)
    {
        const float4* gv = (const float4*)(r + ((size_t)b * Nr + base) * 3);
        float4* sv = (float4*)s;
        const int elems4 = C * 3 / 4;
        for (int t = threadIdx.x; t < elems4; t += BLK) sv[t] = gv[t];
    }
    __syncthreads();

    // load 4 query points (stride-BLK within the block's query window)
    float qx[QPT], qy[QPT], qz[QPT];
    int qi[QPT];
    bool qv[QPT];
#pragma unroll
    for (int k = 0; k < QPT; ++k) {
        qi[k] = blockIdx.x * QPB + k * BLK + threadIdx.x;
        qv[k] = qi[k] < Nq;
        const float* qp = q + ((size_t)b * Nq + (qv[k] ? qi[k] : 0)) * 3;
        qx[k] = qp[0]; qy[k] = qp[1]; qz[k] = qp[2];
    }

    // 4 ref-phase accumulators per query: 16 independent min/argmin chains
    float bd[QPT][4];
    int   bi[QPT][4];
#pragma unroll
    for (int k = 0; k < QPT; ++k)
#pragma unroll
        for (int p = 0; p < 4; ++p) { bd[k][p] = INFINITY; bi[k][p] = base + p; }

    const float4* sv = (const float4*)s;
    const int iters = C / 4;
    for (int j4 = 0; j4 < iters; ++j4) {
        // 12 floats = 4 ref points; all lanes same address -> LDS broadcast
        float4 f0 = sv[3 * j4 + 0];
        float4 f1 = sv[3 * j4 + 1];
        float4 f2 = sv[3 * j4 + 2];
        float px[4] = { f0.x, f0.w, f1.z, f2.y };
        float py[4] = { f0.y, f1.x, f1.w, f2.z };
        float pz[4] = { f0.z, f1.y, f2.x, f2.w };
        const int jb = base + 4 * j4;
#pragma unroll
        for (int p = 0; p < 4; ++p) {
#pragma unroll
            for (int k = 0; k < QPT; ++k) {
                float dx = qx[k] - px[p];
                float dy = qy[k] - py[p];
                float dz = qz[k] - pz[p];
                float d = dx * dx + dy * dy + dz * dz;  // ((x+y)+z), per-op rn
                if (d < bd[k][p]) { bd[k][p] = d; bi[k][p] = jb + p; }
            }
        }
    }

    // merge 4 phases per query; tie-break on lower index (first occurrence)
    const size_t pbase = ((size_t)(dir * B + b) * S + split) * Nq;
#pragma unroll
    for (int k = 0; k < QPT; ++k) {
        float d0 = bd[k][0]; int i0 = bi[k][0];
        float d1 = bd[k][1]; int i1 = bi[k][1];
        float d2 = bd[k][2]; int i2 = bi[k][2];
        float d3 = bd[k][3]; int i3 = bi[k][3];
        if (d1 < d0 || (d1 == d0 && i1 < i0)) { d0 = d1; i0 = i1; }
        if (d3 < d2 || (d3 == d2 && i3 < i2)) { d2 = d3; i2 = i3; }
        if (d2 < d0 || (d2 == d0 && i2 < i0)) { d0 = d2; i0 = i2; }
        if (qv[k]) {
            // d0 >= 0 -> float bits are order-monotonic as unsigned.
            pp[pbase + qi[k]] =
                ((unsigned long long)__float_as_uint(d0) << 32) | (unsigned)i0;
        }
    }
}

__global__ __launch_bounds__(256) void chamfer_merge(
    const unsigned long long* __restrict__ pp,
    float* __restrict__ out, int N, int M, int B, int S)
{
    const int gid = blockIdx.x * blockDim.x + threadIdx.x;
    const int perDir0 = B * N;
    int dir, rem;
    if (gid < perDir0) { dir = 0; rem = gid; }
    else if (gid < perDir0 + B * M) { dir = 1; rem = gid - perDir0; }
    else return;
    const int Nq = dir ? M : N;
    const int b = rem / Nq, i = rem % Nq;

    const size_t base = ((size_t)(dir * B + b) * S) * Nq + i;
    // u64 min == (min dist, then min idx) == first-occurrence argmin.
    unsigned long long best = ~0ULL;
#pragma unroll 8
    for (int sp = 0; sp < S; ++sp) {
        unsigned long long v = pp[base + (size_t)sp * Nq];
        if (v < best) best = v;
    }

    float* dist_out = out + (dir ? (size_t)B * N : 0);
    float* idx_out  = out + (size_t)B * N + (size_t)B * M + (dir ? (size_t)B * N : 0);
    dist_out[(size_t)b * Nq + i] = __uint_as_float((unsigned)(best >> 32));
    idx_out[(size_t)b * Nq + i]  = (float)(unsigned)(best & 0xffffffffu);
}

extern "C" void kernel_launch(void* const* d_in, const int* in_sizes, int n_in,
                              void* d_out, int out_size, void* d_ws, size_t ws_size,
                              hipStream_t stream) {
    const float* xyz1 = (const float*)d_in[0];
    const float* xyz2 = (const float*)d_in[1];
    float* out = (float*)d_out;
    const int B = 4;
    const int N = in_sizes[0] / (B * 3);
    const int M = in_sizes[1] / (B * 3);
    const int NQ = (N > M ? N : M);
    const int NR = (N > M ? N : M);

    // pick split count S (pow2) such that packed partials fit in ws
    int S = 32;
    while (S > 1 && (size_t)2 * B * S * NQ * 8 > ws_size) S >>= 1;
    while (NR % S) S >>= 1;  // require exact divisibility
    const int C = NR / S;

    unsigned long long* pp = (unsigned long long*)d_ws;

    dim3 grid((NQ + QPB - 1) / QPB, B * S, 2);
    size_t lds = (size_t)C * 3 * sizeof(float);
    chamfer_main<<<grid, dim3(BLK, 1, 1), lds, stream>>>(
        xyz1, xyz2, pp, N, M, B, S, C);

    int totalOut = 2 * B * NQ;
    chamfer_merge<<<dim3((totalOut + 255) / 256, 1, 1), dim3(256, 1, 1), 0, stream>>>(
        pp, out, N, M, B, S);
}

// Round 5
// 170.102 us; speedup vs baseline: 4.2007x; 1.0303x over previous
//
#include <hip/hip_runtime.h>
#include <math.h>

// Chamfer distance, B=4, N=M=8192, fp32.
// Output layout (flat float32): dist1[B*N], dist2[B*M], idx1[B*N] (as float),
// idx2[B*M] (as float).
//
// R4: (a) merge via device-scope u64 atomicMin of packed (dist_bits<<32|idx)
// — u64 min == (min dist, tie -> lower idx) == first-occurrence argmin;
// kills the 44us merge-kernel tail from R3. (b) 8 ref points per inner iter
// (6x ds_read_b128, 32 evals/iter) to amortize per-iter bookkeeping.
// Inner-loop arithmetic unchanged: per-op IEEE rounding (contract off),
// strict < => absmax 0 vs numpy.

#define QPT 4         // queries per thread
#define BLK 256       // threads per block
#define QPB (QPT*BLK) // queries per block = 1024

__global__ __launch_bounds__(256) void chamfer_init(
    unsigned long long* __restrict__ pp, int n)
{
    int i = blockIdx.x * blockDim.x + threadIdx.x;
    if (i < n) pp[i] = ~0ULL;
}

__global__ __launch_bounds__(256, 4) void chamfer_main(
    const float* __restrict__ xyz1, const float* __restrict__ xyz2,
    unsigned long long* __restrict__ pp,
    int N, int M, int B, int S, int C)
{
#pragma clang fp contract(off)  // match numpy per-op IEEE rounding (no fma fuse)
    const int dir = blockIdx.z;          // 0: xyz1->xyz2, 1: xyz2->xyz1
    const float* q = dir ? xyz2 : xyz1;  // query cloud
    const float* r = dir ? xyz1 : xyz2;  // reference cloud
    const int Nq = dir ? M : N;
    const int Nr = dir ? N : M;
    const int b     = blockIdx.y / S;
    const int split = blockIdx.y % S;
    const int base  = split * C;         // this block's ref-index range [base, base+C)

    extern __shared__ float s[];         // C*3 floats

    // cooperative vectorized tile load (C%8==0 -> byte count divisible by 16)
    {
        const float4* gv = (const float4*)(r + ((size_t)b * Nr + base) * 3);
        float4* sv = (float4*)s;
        const int elems4 = C * 3 / 4;
        for (int t = threadIdx.x; t < elems4; t += BLK) sv[t] = gv[t];
    }
    __syncthreads();

    // load 4 query points (stride-BLK within the block's query window)
    float qx[QPT], qy[QPT], qz[QPT];
    int qi[QPT];
    bool qv[QPT];
#pragma unroll
    for (int k = 0; k < QPT; ++k) {
        qi[k] = blockIdx.x * QPB + k * BLK + threadIdx.x;
        qv[k] = qi[k] < Nq;
        const float* qp = q + ((size_t)b * Nq + (qv[k] ? qi[k] : 0)) * 3;
        qx[k] = qp[0]; qy[k] = qp[1]; qz[k] = qp[2];
    }

    // 4 accumulator phases per query: 16 independent min/argmin chains.
    // Each phase is updated twice per iter in ascending index order (strict <)
    // so first-occurrence argmin is preserved.
    float bd[QPT][4];
    int   bi[QPT][4];
#pragma unroll
    for (int k = 0; k < QPT; ++k)
#pragma unroll
        for (int p = 0; p < 4; ++p) { bd[k][p] = INFINITY; bi[k][p] = base + p; }

    const float4* sv = (const float4*)s;
    const int iters = C / 8;
    for (int j8 = 0; j8 < iters; ++j8) {
        // 24 floats = 8 ref points; all lanes same address -> LDS broadcast
        float4 f0 = sv[6 * j8 + 0];
        float4 f1 = sv[6 * j8 + 1];
        float4 f2 = sv[6 * j8 + 2];
        float4 f3 = sv[6 * j8 + 3];
        float4 f4 = sv[6 * j8 + 4];
        float4 f5 = sv[6 * j8 + 5];
        float px[8] = { f0.x, f0.w, f1.z, f2.y, f3.x, f3.w, f4.z, f5.y };
        float py[8] = { f0.y, f1.x, f1.w, f2.z, f3.y, f4.x, f4.w, f5.z };
        float pz[8] = { f0.z, f1.y, f2.x, f2.w, f3.z, f4.y, f5.x, f5.w };
        const int jb = base + 8 * j8;
#pragma unroll
        for (int p = 0; p < 8; ++p) {
#pragma unroll
            for (int k = 0; k < QPT; ++k) {
                float dx = qx[k] - px[p];
                float dy = qy[k] - py[p];
                float dz = qz[k] - pz[p];
                float d = dx * dx + dy * dy + dz * dz;  // ((x+y)+z), per-op rn
                if (d < bd[k][p & 3]) { bd[k][p & 3] = d; bi[k][p & 3] = jb + p; }
            }
        }
    }

    // merge 4 phases per query; tie-break on lower index (first occurrence);
    // then fold into the global per-query slot via u64 atomicMin.
    const size_t obase = (size_t)(dir * B + b) * Nq;
#pragma unroll
    for (int k = 0; k < QPT; ++k) {
        float d0 = bd[k][0]; int i0 = bi[k][0];
        float d1 = bd[k][1]; int i1 = bi[k][1];
        float d2 = bd[k][2]; int i2 = bi[k][2];
        float d3 = bd[k][3]; int i3 = bi[k][3];
        if (d1 < d0 || (d1 == d0 && i1 < i0)) { d0 = d1; i0 = i1; }
        if (d3 < d2 || (d3 == d2 && i3 < i2)) { d2 = d3; i2 = i3; }
        if (d2 < d0 || (d2 == d0 && i2 < i0)) { d0 = d2; i0 = i2; }
        if (qv[k]) {
            // d0 >= 0 -> float bits order-monotonic as unsigned.
            unsigned long long packed =
                ((unsigned long long)__float_as_uint(d0) << 32) | (unsigned)i0;
            atomicMin(&pp[obase + qi[k]], packed);
        }
    }
}

__global__ __launch_bounds__(256) void chamfer_final(
    const unsigned long long* __restrict__ pp,
    float* __restrict__ out, int N, int M, int B)
{
    const int gid = blockIdx.x * blockDim.x + threadIdx.x;
    const int perDir0 = B * N;
    int dir, rem;
    if (gid < perDir0) { dir = 0; rem = gid; }
    else if (gid < perDir0 + B * M) { dir = 1; rem = gid - perDir0; }
    else return;
    const int Nq = dir ? M : N;

    unsigned long long v = pp[(size_t)dir * B * (dir ? M : N) ? 0 : 0];  // placeholder avoid
    v = pp[(size_t)(dir * B) * Nq + rem];  // pp is [2][B][Nq] flat; rem = b*Nq+i

    float* dist_out = out + (dir ? (size_t)B * N : 0);
    float* idx_out  = out + (size_t)B * N + (size_t)B * M + (dir ? (size_t)B * N : 0);
    dist_out[rem] = __uint_as_float((unsigned)(v >> 32));
    idx_out[rem]  = (float)(unsigned)(v & 0xffffffffu);
}

extern "C" void kernel_launch(void* const* d_in, const int* in_sizes, int n_in,
                              void* d_out, int out_size, void* d_ws, size_t ws_size,
                              hipStream_t stream) {
    const float* xyz1 = (const float*)d_in[0];
    const float* xyz2 = (const float*)d_in[1];
    float* out = (float*)d_out;
    const int B = 4;
    const int N = in_sizes[0] / (B * 3);
    const int M = in_sizes[1] / (B * 3);
    const int NQ = (N > M ? N : M);
    const int NR = (N > M ? N : M);

    int S = 32;
    while (NR % (S * 8)) S >>= 1;  // need C = NR/S divisible by 8
    const int C = NR / S;

    unsigned long long* pp = (unsigned long long*)d_ws;  // [2][B][NQ] packed slots
    const int nslots = 2 * B * NQ;

    chamfer_init<<<dim3((nslots + 255) / 256, 1, 1), dim3(256, 1, 1), 0, stream>>>(
        pp, nslots);

    dim3 grid((NQ + QPB - 1) / QPB, B * S, 2);
    size_t lds = (size_t)C * 3 * sizeof(float);
    chamfer_main<<<grid, dim3(BLK, 1, 1), lds, stream>>>(
        xyz1, xyz2, pp, N, M, B, S, C);

    chamfer_final<<<dim3((nslots + 255) / 256, 1, 1), dim3(256, 1, 1), 0, stream>>>(
        pp, out, N, M, B);
}

// Round 6
// 155.437 us; speedup vs baseline: 4.5970x; 1.0943x over previous
//
#include <hip/hip_runtime.h>
#include <math.h>

// Chamfer distance, B=4, N=M=8192, fp32.
// Output layout (flat float32): dist1[B*N], dist2[B*M], idx1[B*N] (as float),
// idx2[B*M] (as float).
//
// R5: inner distance uses explicit fma form d = fma(dx,dx, fma(dy,dy, dz*dz))
// (6 arith insts vs 8 for the contract-off form). All intermediates have the
// magnitude of d itself, so the discrepancy vs the reference's
// ((dx*dx+dy*dy)+dz*dz) per-op rounding is <= ~3 ulp(d) ~ 1.5e-9 absolute —
// ~2300x smaller than typical top-2 gaps (3.4e-3), so argmin is flip-safe
// (expected flips ~0.03 over the whole fixed dataset). Dist output differs by
// ~1e-9 << threshold. Merge via u64 atomicMin of (dist_bits<<32|idx): u64 min
// == (min dist, tie -> lower idx) == first-occurrence argmin.

#define QPT 4         // queries per thread
#define BLK 256       // threads per block
#define QPB (QPT*BLK) // queries per block = 1024

__global__ __launch_bounds__(256) void chamfer_init(
    unsigned long long* __restrict__ pp, int n)
{
    int i = blockIdx.x * blockDim.x + threadIdx.x;
    if (i < n) pp[i] = ~0ULL;
}

__global__ __launch_bounds__(256, 4) void chamfer_main(
    const float* __restrict__ xyz1, const float* __restrict__ xyz2,
    unsigned long long* __restrict__ pp,
    int N, int M, int B, int S, int C)
{
    const int dir = blockIdx.z;          // 0: xyz1->xyz2, 1: xyz2->xyz1
    const float* q = dir ? xyz2 : xyz1;  // query cloud
    const float* r = dir ? xyz1 : xyz2;  // reference cloud
    const int Nq = dir ? M : N;
    const int Nr = dir ? N : M;
    const int b     = blockIdx.y / S;
    const int split = blockIdx.y % S;
    const int base  = split * C;         // this block's ref-index range [base, base+C)

    extern __shared__ float s[];         // C*3 floats

    // cooperative vectorized tile load (C%8==0 -> byte count divisible by 16)
    {
        const float4* gv = (const float4*)(r + ((size_t)b * Nr + base) * 3);
        float4* sv = (float4*)s;
        const int elems4 = C * 3 / 4;
        for (int t = threadIdx.x; t < elems4; t += BLK) sv[t] = gv[t];
    }
    __syncthreads();

    // load 4 query points (stride-BLK within the block's query window)
    float qx[QPT], qy[QPT], qz[QPT];
    int qi[QPT];
    bool qv[QPT];
#pragma unroll
    for (int k = 0; k < QPT; ++k) {
        qi[k] = blockIdx.x * QPB + k * BLK + threadIdx.x;
        qv[k] = qi[k] < Nq;
        const float* qp = q + ((size_t)b * Nq + (qv[k] ? qi[k] : 0)) * 3;
        qx[k] = qp[0]; qy[k] = qp[1]; qz[k] = qp[2];
    }

    // 4 accumulator phases per query: 16 independent min/argmin chains.
    // Each phase is updated twice per iter in ascending index order (strict <)
    // so first-occurrence argmin is preserved.
    float bd[QPT][4];
    int   bi[QPT][4];
#pragma unroll
    for (int k = 0; k < QPT; ++k)
#pragma unroll
        for (int p = 0; p < 4; ++p) { bd[k][p] = INFINITY; bi[k][p] = base + p; }

    const float4* sv = (const float4*)s;
    const int iters = C / 8;
    for (int j8 = 0; j8 < iters; ++j8) {
        // 24 floats = 8 ref points; all lanes same address -> LDS broadcast
        float4 f0 = sv[6 * j8 + 0];
        float4 f1 = sv[6 * j8 + 1];
        float4 f2 = sv[6 * j8 + 2];
        float4 f3 = sv[6 * j8 + 3];
        float4 f4 = sv[6 * j8 + 4];
        float4 f5 = sv[6 * j8 + 5];
        float px[8] = { f0.x, f0.w, f1.z, f2.y, f3.x, f3.w, f4.z, f5.y };
        float py[8] = { f0.y, f1.x, f1.w, f2.z, f3.y, f4.x, f4.w, f5.z };
        float pz[8] = { f0.z, f1.y, f2.x, f2.w, f3.z, f4.y, f5.x, f5.w };
        const int jb = base + 8 * j8;
#pragma unroll
        for (int p = 0; p < 8; ++p) {
#pragma unroll
            for (int k = 0; k < QPT; ++k) {
                float dx = qx[k] - px[p];
                float dy = qy[k] - py[p];
                float dz = qz[k] - pz[p];
                // 6 insts: 3 sub, 1 mul, 2 fma. Same-magnitude intermediates
                // keep the rounding delta vs reference at ~ulp(d) (flip-safe).
                float d = fmaf(dx, dx, fmaf(dy, dy, dz * dz));
                bool c = d < bd[k][p & 3];
                bd[k][p & 3] = c ? d : bd[k][p & 3];
                bi[k][p & 3] = c ? (jb + p) : bi[k][p & 3];
            }
        }
    }

    // merge 4 phases per query; tie-break on lower index (first occurrence);
    // then fold into the global per-query slot via u64 atomicMin.
    const size_t obase = (size_t)(dir * B + b) * Nq;
#pragma unroll
    for (int k = 0; k < QPT; ++k) {
        float d0 = bd[k][0]; int i0 = bi[k][0];
        float d1 = bd[k][1]; int i1 = bi[k][1];
        float d2 = bd[k][2]; int i2 = bi[k][2];
        float d3 = bd[k][3]; int i3 = bi[k][3];
        if (d1 < d0 || (d1 == d0 && i1 < i0)) { d0 = d1; i0 = i1; }
        if (d3 < d2 || (d3 == d2 && i3 < i2)) { d2 = d3; i2 = i3; }
        if (d2 < d0 || (d2 == d0 && i2 < i0)) { d0 = d2; i0 = i2; }
        if (qv[k]) {
            // d0 >= 0 -> float bits order-monotonic as unsigned.
            unsigned long long packed =
                ((unsigned long long)__float_as_uint(d0) << 32) | (unsigned)i0;
            atomicMin(&pp[obase + qi[k]], packed);
        }
    }
}

__global__ __launch_bounds__(256) void chamfer_final(
    const unsigned long long* __restrict__ pp,
    float* __restrict__ out, int N, int M, int B)
{
    const int gid = blockIdx.x * blockDim.x + threadIdx.x;
    const int perDir0 = B * N;
    int dir, rem;
    if (gid < perDir0) { dir = 0; rem = gid; }
    else if (gid < perDir0 + B * M) { dir = 1; rem = gid - perDir0; }
    else return;
    const int Nq = dir ? M : N;

    // pp is [2][B][Nq] flat; rem = b*Nq + i
    unsigned long long v = pp[(size_t)(dir * B) * Nq + rem];

    float* dist_out = out + (dir ? (size_t)B * N : 0);
    float* idx_out  = out + (size_t)B * N + (size_t)B * M + (dir ? (size_t)B * N : 0);
    dist_out[rem] = __uint_as_float((unsigned)(v >> 32));
    idx_out[rem]  = (float)(unsigned)(v & 0xffffffffu);
}

extern "C" void kernel_launch(void* const* d_in, const int* in_sizes, int n_in,
                              void* d_out, int out_size, void* d_ws, size_t ws_size,
                              hipStream_t stream) {
    const float* xyz1 = (const float*)d_in[0];
    const float* xyz2 = (const float*)d_in[1];
    float* out = (float*)d_out;
    const int B = 4;
    const int N = in_sizes[0] / (B * 3);
    const int M = in_sizes[1] / (B * 3);
    const int NQ = (N > M ? N : M);
    const int NR = (N > M ? N : M);

    int S = 32;
    while (NR % (S * 8)) S >>= 1;  // need C = NR/S divisible by 8
    const int C = NR / S;

    unsigned long long* pp = (unsigned long long*)d_ws;  // [2][B][NQ] packed slots
    const int nslots = 2 * B * NQ;

    chamfer_init<<<dim3((nslots + 255) / 256, 1, 1), dim3(256, 1, 1), 0, stream>>>(
        pp, nslots);

    dim3 grid((NQ + QPB - 1) / QPB, B * S, 2);
    size_t lds = (size_t)C * 3 * sizeof(float);
    chamfer_main<<<grid, dim3(BLK, 1, 1), lds, stream>>>(
        xyz1, xyz2, pp, N, M, B, S, C);

    chamfer_final<<<dim3((nslots + 255) / 256, 1, 1), dim3(256, 1, 1), 0, stream>>>(
        pp, out, N, M, B);
}

// Round 7
// 125.170 us; speedup vs baseline: 5.7086x; 1.2418x over previous
//
#include <hip/hip_runtime.h>
#include <math.h>

// Chamfer distance, B=4, N=M=8192, fp32.
// Output layout (flat float32): dist1[B*N], dist2[B*M], idx1[B*N] (as float),
// idx2[B*M] (as float).
//
// R6: group-of-8 min-tree argmin. Inner loop per 8 ref points per query:
// 8 exact distances (fma form, same values as R5 -> absmax 0), fminf tree
// (folds to v_min3), ONE strict-< (bd, group) update -> ~6.9 VALU insts/eval
// vs 9. Winning group's intra-index resolved once per tile by deterministic
// recompute (LDS tile still resident) with a descending equality scan ->
// smallest p == first occurrence. Strict < keeps earliest group; u64
// atomicMin of (dist_bits<<32|idx) tie-breaks to lower global index ==
// np.argmin first-occurrence semantics.

#define QPT 4         // queries per thread
#define BLK 256       // threads per block
#define QPB (QPT*BLK) // queries per block = 1024

__global__ __launch_bounds__(256) void chamfer_init(
    unsigned long long* __restrict__ pp, int n)
{
    int i = blockIdx.x * blockDim.x + threadIdx.x;
    if (i < n) pp[i] = ~0ULL;
}

__global__ __launch_bounds__(256, 4) void chamfer_main(
    const float* __restrict__ xyz1, const float* __restrict__ xyz2,
    unsigned long long* __restrict__ pp,
    int N, int M, int B, int S, int C)
{
    const int dir = blockIdx.z;          // 0: xyz1->xyz2, 1: xyz2->xyz1
    const float* q = dir ? xyz2 : xyz1;  // query cloud
    const float* r = dir ? xyz1 : xyz2;  // reference cloud
    const int Nq = dir ? M : N;
    const int Nr = dir ? N : M;
    const int b     = blockIdx.y / S;
    const int split = blockIdx.y % S;
    const int base  = split * C;         // this block's ref-index range [base, base+C)

    extern __shared__ float s[];         // C*3 floats

    // cooperative vectorized tile load (C%8==0 -> byte count divisible by 16)
    {
        const float4* gv = (const float4*)(r + ((size_t)b * Nr + base) * 3);
        float4* sv = (float4*)s;
        const int elems4 = C * 3 / 4;
        for (int t = threadIdx.x; t < elems4; t += BLK) sv[t] = gv[t];
    }
    __syncthreads();

    // load 4 query points (stride-BLK within the block's query window)
    float qx[QPT], qy[QPT], qz[QPT];
    int qi[QPT];
    bool qv[QPT];
#pragma unroll
    for (int k = 0; k < QPT; ++k) {
        qi[k] = blockIdx.x * QPB + k * BLK + threadIdx.x;
        qv[k] = qi[k] < Nq;
        const float* qp = q + ((size_t)b * Nq + (qv[k] ? qi[k] : 0)) * 3;
        qx[k] = qp[0]; qy[k] = qp[1]; qz[k] = qp[2];
    }

    // per-query running min + winning 8-group id
    float bd[QPT];
    int   gi[QPT];
#pragma unroll
    for (int k = 0; k < QPT; ++k) { bd[k] = INFINITY; gi[k] = 0; }

    const float4* sv = (const float4*)s;
    const int iters = C / 8;
    for (int j8 = 0; j8 < iters; ++j8) {
        // 24 floats = 8 ref points; all lanes same address -> LDS broadcast
        float4 f0 = sv[6 * j8 + 0];
        float4 f1 = sv[6 * j8 + 1];
        float4 f2 = sv[6 * j8 + 2];
        float4 f3 = sv[6 * j8 + 3];
        float4 f4 = sv[6 * j8 + 4];
        float4 f5 = sv[6 * j8 + 5];
        float px[8] = { f0.x, f0.w, f1.z, f2.y, f3.x, f3.w, f4.z, f5.y };
        float py[8] = { f0.y, f1.x, f1.w, f2.z, f3.y, f4.x, f4.w, f5.z };
        float pz[8] = { f0.z, f1.y, f2.x, f2.w, f3.z, f4.y, f5.x, f5.w };
#pragma unroll
        for (int k = 0; k < QPT; ++k) {
            float d[8];
#pragma unroll
            for (int p = 0; p < 8; ++p) {
                float dx = qx[k] - px[p];
                float dy = qy[k] - py[p];
                float dz = qz[k] - pz[p];
                d[p] = fmaf(dx, dx, fmaf(dy, dy, dz * dz));
            }
            // min-of-8 tree (compiler folds fminf pairs/triples into v_min3)
            float m01 = fminf(d[0], d[1]);
            float m23 = fminf(d[2], d[3]);
            float m45 = fminf(d[4], d[5]);
            float m67 = fminf(d[6], d[7]);
            float m = fminf(fminf(m01, m23), fminf(m45, m67));
            // strict < keeps the EARLIEST group attaining the min value
            if (m < bd[k]) { bd[k] = m; gi[k] = j8; }
        }
    }

    // resolve intra-group index of the winner by deterministic recompute
    // (same fmaf expression on the same LDS data -> bitwise identical d),
    // then fold into the global per-query slot via u64 atomicMin.
    const size_t obase = (size_t)(dir * B + b) * Nq;
#pragma unroll
    for (int k = 0; k < QPT; ++k) {
        if (!qv[k]) continue;
        const int g = gi[k];
        float4 f0 = sv[6 * g + 0];
        float4 f1 = sv[6 * g + 1];
        float4 f2 = sv[6 * g + 2];
        float4 f3 = sv[6 * g + 3];
        float4 f4 = sv[6 * g + 4];
        float4 f5 = sv[6 * g + 5];
        float px[8] = { f0.x, f0.w, f1.z, f2.y, f3.x, f3.w, f4.z, f5.y };
        float py[8] = { f0.y, f1.x, f1.w, f2.z, f3.y, f4.x, f4.w, f5.z };
        float pz[8] = { f0.z, f1.y, f2.x, f2.w, f3.z, f4.y, f5.x, f5.w };
        int best = 0;
#pragma unroll
        for (int p = 7; p >= 0; --p) {   // descending: ends at SMALLEST match
            float dx = qx[k] - px[p];
            float dy = qy[k] - py[p];
            float dz = qz[k] - pz[p];
            float d = fmaf(dx, dx, fmaf(dy, dy, dz * dz));
            if (d == bd[k]) best = p;    // match guaranteed (same bits)
        }
        const int idx = base + g * 8 + best;
        // d >= 0 -> float bits order-monotonic as unsigned.
        unsigned long long packed =
            ((unsigned long long)__float_as_uint(bd[k]) << 32) | (unsigned)idx;
        atomicMin(&pp[obase + qi[k]], packed);
    }
}

__global__ __launch_bounds__(256) void chamfer_final(
    const unsigned long long* __restrict__ pp,
    float* __restrict__ out, int N, int M, int B)
{
    const int gid = blockIdx.x * blockDim.x + threadIdx.x;
    const int perDir0 = B * N;
    int dir, rem;
    if (gid < perDir0) { dir = 0; rem = gid; }
    else if (gid < perDir0 + B * M) { dir = 1; rem = gid - perDir0; }
    else return;
    const int Nq = dir ? M : N;

    // pp is [2][B][Nq] flat; rem = b*Nq + i
    unsigned long long v = pp[(size_t)(dir * B) * Nq + rem];

    float* dist_out = out + (dir ? (size_t)B * N : 0);
    float* idx_out  = out + (size_t)B * N + (size_t)B * M + (dir ? (size_t)B * N : 0);
    dist_out[rem] = __uint_as_float((unsigned)(v >> 32));
    idx_out[rem]  = (float)(unsigned)(v & 0xffffffffu);
}

extern "C" void kernel_launch(void* const* d_in, const int* in_sizes, int n_in,
                              void* d_out, int out_size, void* d_ws, size_t ws_size,
                              hipStream_t stream) {
    const float* xyz1 = (const float*)d_in[0];
    const float* xyz2 = (const float*)d_in[1];
    float* out = (float*)d_out;
    const int B = 4;
    const int N = in_sizes[0] / (B * 3);
    const int M = in_sizes[1] / (B * 3);
    const int NQ = (N > M ? N : M);
    const int NR = (N > M ? N : M);

    int S = 32;
    while (NR % (S * 8)) S >>= 1;  // need C = NR/S divisible by 8
    const int C = NR / S;

    unsigned long long* pp = (unsigned long long*)d_ws;  // [2][B][NQ] packed slots
    const int nslots = 2 * B * NQ;

    chamfer_init<<<dim3((nslots + 255) / 256, 1, 1), dim3(256, 1, 1), 0, stream>>>(
        pp, nslots);

    dim3 grid((NQ + QPB - 1) / QPB, B * S, 2);
    size_t lds = (size_t)C * 3 * sizeof(float);
    chamfer_main<<<grid, dim3(BLK, 1, 1), lds, stream>>>(
        xyz1, xyz2, pp, N, M, B, S, C);

    chamfer_final<<<dim3((nslots + 255) / 256, 1, 1), dim3(256, 1, 1), 0, stream>>>(
        pp, out, N, M, B);
}